// Round 3
// baseline (1028.614 us; speedup 1.0000x reference)
//
#include <hip/hip_runtime.h>
#include <math.h>

// OCRHead optimized decomposition:
//   attn  = softmax(ctx)                                  [B,K,HW]
//   ocr   = Feature @ attn^T  (per b: [C,HW]x[HW,K])      [B,C,K]
//   ocr2  = W1 @ ocr          (tiny GEMM, replaces 1x1 conv on full map)
//   rel   = ocr^T @ Feature                               [B,K,HW]
//   attn2 = softmax(rel)      (in place)
//   w2a[b]= w2_left . ocr2[b] (19x19x9), bcon = w2_left . b1
//   out   = b2 + masked(bcon) + conv3x3(attn2, w2a) + conv3x3(feature, w2_right)

#define BB 4
#define KK 19
#define CC 512
#define HH 128
#define WW 128
#define HWHW (HH*WW)

// ---------------- softmax over rows of length HW ----------------
__global__ __launch_bounds__(256) void softmax_rows(const float* __restrict__ in,
                                                    float* __restrict__ out) {
    int row = blockIdx.x;
    const float* r = in + (size_t)row * HWHW;
    float* o = out + (size_t)row * HWHW;
    int t = threadIdx.x;
    float v[64];
    float m = -1e30f;
#pragma unroll
    for (int i = 0; i < 64; ++i) { v[i] = r[t + i * 256]; m = fmaxf(m, v[i]); }
    for (int off = 32; off; off >>= 1) m = fmaxf(m, __shfl_xor(m, off));
    __shared__ float sm[4], ss[4];
    int wave = t >> 6;
    if ((t & 63) == 0) sm[wave] = m;
    __syncthreads();
    m = fmaxf(fmaxf(sm[0], sm[1]), fmaxf(sm[2], sm[3]));
    float s = 0.f;
#pragma unroll
    for (int i = 0; i < 64; ++i) { v[i] = __expf(v[i] - m); s += v[i]; }
    for (int off = 32; off; off >>= 1) s += __shfl_xor(s, off);
    if ((t & 63) == 0) ss[wave] = s;
    __syncthreads();
    s = ss[0] + ss[1] + ss[2] + ss[3];
    float inv = 1.f / s;
#pragma unroll
    for (int i = 0; i < 64; ++i) o[t + i * 256] = v[i] * inv;
}

// ---------------- ocr[b,c,k] = sum_n attn[b,k,n]*feature[b,c,n] ----------------
// grid (32 ctiles, B, 8 n-slices), block 256 (4 waves x 4 channels each)
#define NSPLIT 8
__global__ __launch_bounds__(256) void ocr_kernel(const float* __restrict__ feature,
                                                  const float* __restrict__ attn,
                                                  float* __restrict__ ocr) {
    int ctile = blockIdx.x, b = blockIdx.y, ns = blockIdx.z;
    int t = threadIdx.x, wave = t >> 6, lane = t & 63;
    int c0 = ctile * 16 + wave * 4;
    const float* fbase = feature + (size_t)b * CC * HWHW;
    const float* abase = attn + (size_t)b * KK * HWHW;
    float acc[4][KK];
#pragma unroll
    for (int j = 0; j < 4; ++j)
#pragma unroll
        for (int k = 0; k < KK; ++k) acc[j][k] = 0.f;
    int nstart = ns * (HWHW / NSPLIT);
    for (int it = 0; it < (HWHW / NSPLIT) / 64; ++it) {
        int n = nstart + it * 64 + lane;
        float a[KK];
#pragma unroll
        for (int k = 0; k < KK; ++k) a[k] = abase[(size_t)k * HWHW + n];
#pragma unroll
        for (int j = 0; j < 4; ++j) {
            float f = fbase[(size_t)(c0 + j) * HWHW + n];
#pragma unroll
            for (int k = 0; k < KK; ++k) acc[j][k] += f * a[k];
        }
    }
#pragma unroll
    for (int j = 0; j < 4; ++j)
#pragma unroll
        for (int k = 0; k < KK; ++k) {
            float x = acc[j][k];
            for (int off = 32; off; off >>= 1) x += __shfl_xor(x, off);
            if (lane == 0) atomicAdd(&ocr[((size_t)b * CC + (c0 + j)) * KK + k], x);
        }
}

// ---------------- ocr2[b,co,k] = sum_ci w1[co,ci]*ocr[b,ci,k] ----------------
// grid (C, B), block 64
__global__ __launch_bounds__(64) void ocr2_kernel(const float* __restrict__ w1,
                                                  const float* __restrict__ ocr,
                                                  float* __restrict__ ocr2) {
    int co = blockIdx.x, b = blockIdx.y, lane = threadIdx.x;
    float acc[KK];
#pragma unroll
    for (int k = 0; k < KK; ++k) acc[k] = 0.f;
    const float* wrow = w1 + (size_t)co * CC;
    const float* ob = ocr + (size_t)b * CC * KK;
    for (int ci = lane; ci < CC; ci += 64) {
        float w = wrow[ci];
#pragma unroll
        for (int k = 0; k < KK; ++k) acc[k] += w * ob[ci * KK + k];
    }
#pragma unroll
    for (int k = 0; k < KK; ++k) {
        float x = acc[k];
        for (int off = 32; off; off >>= 1) x += __shfl_xor(x, off);
        if (lane == 0) ocr2[((size_t)b * CC + co) * KK + k] = x;
    }
}

// ---------------- transpose right-half conv weights: wTr[c][ko*9+dydx] ----------------
__global__ __launch_bounds__(256) void wtr_kernel(const float* __restrict__ w2,
                                                  float* __restrict__ wTr) {
    int idx = blockIdx.x * 256 + threadIdx.x;
    if (idx >= CC * 171) return;
    int c = idx / 171, j = idx % 171;
    int ko = j / 9, dydx = j % 9;
    wTr[idx] = w2[((size_t)ko * (2 * CC) + CC + c) * 9 + dydx];
}

// ---------------- w2a[b,ko,k,dydx] = sum_c w2[ko,c,dydx]*ocr2[b,c,k]; bcon = w2_left.b1 ----------------
// grid (19, 9, B), block 64
__global__ __launch_bounds__(64) void w2a_kernel(const float* __restrict__ w2,
                                                 const float* __restrict__ ocr2,
                                                 const float* __restrict__ b1,
                                                 float* __restrict__ w2a,
                                                 float* __restrict__ bcon) {
    int ko = blockIdx.x, dydx = blockIdx.y, b = blockIdx.z, lane = threadIdx.x;
    float acc[KK];
#pragma unroll
    for (int k = 0; k < KK; ++k) acc[k] = 0.f;
    float accb = 0.f;
    for (int c = lane; c < CC; c += 64) {
        float wv = w2[((size_t)ko * (2 * CC) + c) * 9 + dydx];
#pragma unroll
        for (int k = 0; k < KK; ++k) acc[k] += wv * ocr2[((size_t)b * CC + c) * KK + k];
        accb += wv * b1[c];
    }
#pragma unroll
    for (int k = 0; k < KK; ++k) {
        float x = acc[k];
        for (int off = 32; off; off >>= 1) x += __shfl_xor(x, off);
        if (lane == 0) w2a[(((size_t)b * KK + ko) * KK + k) * 9 + dydx] = x;
    }
    for (int off = 32; off; off >>= 1) accb += __shfl_xor(accb, off);
    if (lane == 0 && b == 0) bcon[ko * 9 + dydx] = accb;
}

// ---------------- rel[b,k,n] = sum_c feature[b,c,n]*ocr[b,c,k] ----------------
// grid (HW/256, B), block 256
__global__ __launch_bounds__(256) void rel_kernel(const float* __restrict__ feature,
                                                  const float* __restrict__ ocr,
                                                  float* __restrict__ rel) {
    int b = blockIdx.y;
    int n = blockIdx.x * 256 + threadIdx.x;
    const float* fb = feature + (size_t)b * CC * HWHW + n;
    const float* ob = ocr + (size_t)b * CC * KK;  // wave-uniform reads -> s_load
    float acc[KK];
#pragma unroll
    for (int k = 0; k < KK; ++k) acc[k] = 0.f;
    for (int ci = 0; ci < CC; ++ci) {
        float f = fb[(size_t)ci * HWHW];
#pragma unroll
        for (int k = 0; k < KK; ++k) acc[k] += ob[ci * KK + k] * f;
    }
#pragma unroll
    for (int k = 0; k < KK; ++k) rel[((size_t)b * KK + k) * HWHW + n] = acc[k];
}

// ---------------- final: out = b2 + masked bcon + conv(attn2,w2a) + conv(feature,wTr) ----------------
// grid (64 ytiles, B), block 256 (2 rows of 128)
__global__ __launch_bounds__(256) void out_kernel(const float* __restrict__ feature,
                                                  const float* __restrict__ attn2,
                                                  const float* __restrict__ wTr,
                                                  const float* __restrict__ w2a,
                                                  const float* __restrict__ bcon,
                                                  const float* __restrict__ b2,
                                                  float* __restrict__ out) {
    int b = blockIdx.y;
    int t = threadIdx.x;
    int y = blockIdx.x * 2 + (t >> 7);
    int x = t & 127;

    float m[9];
    int off[9];
#pragma unroll
    for (int dy = -1; dy <= 1; ++dy)
#pragma unroll
        for (int dx = -1; dx <= 1; ++dx) {
            int i = (dy + 1) * 3 + (dx + 1);
            int yy = y + dy, xx = x + dx;
            bool valid = (yy >= 0 && yy < HH && xx >= 0 && xx < WW);
            m[i] = valid ? 1.f : 0.f;
            int yc = min(max(yy, 0), HH - 1), xc = min(max(xx, 0), WW - 1);
            off[i] = yc * WW + xc;
        }

    float acc[KK];
#pragma unroll
    for (int ko = 0; ko < KK; ++ko) acc[ko] = b2[ko];
#pragma unroll
    for (int i = 0; i < 9; ++i)
#pragma unroll
        for (int ko = 0; ko < KK; ++ko) acc[ko] += m[i] * bcon[ko * 9 + i];

    // attn2 (rank-19) part
    const float* a2b = attn2 + (size_t)b * KK * HWHW;
    const float* wab = w2a + (size_t)b * KK * KK * 9;
    for (int k = 0; k < KK; ++k) {
        float tap[9];
#pragma unroll
        for (int i = 0; i < 9; ++i) tap[i] = m[i] * a2b[(size_t)k * HWHW + off[i]];
#pragma unroll
        for (int ko = 0; ko < KK; ++ko)
#pragma unroll
            for (int i = 0; i < 9; ++i) acc[ko] += wab[(ko * KK + k) * 9 + i] * tap[i];
    }

    // feature conv part (weights read wave-uniform -> scalar path)
    const float* fb = feature + (size_t)b * CC * HWHW;
    for (int cc = 0; cc < CC; ++cc) {
        float tap[9];
#pragma unroll
        for (int i = 0; i < 9; ++i) tap[i] = m[i] * fb[(size_t)cc * HWHW + off[i]];
        const float* wr = wTr + cc * 171;
#pragma unroll
        for (int j = 0; j < 171; ++j) acc[j / 9] += wr[j] * tap[j % 9];
    }

    size_t obase = ((size_t)b * KK) * HWHW + (size_t)y * WW + x;
#pragma unroll
    for (int ko = 0; ko < KK; ++ko) out[obase + (size_t)ko * HWHW] = acc[ko];
}

extern "C" void kernel_launch(void* const* d_in, const int* in_sizes, int n_in,
                              void* d_out, int out_size, void* d_ws, size_t ws_size,
                              hipStream_t stream) {
    const float* ctx = (const float*)d_in[0];
    const float* feature = (const float*)d_in[1];
    const float* w1 = (const float*)d_in[2];
    const float* b1 = (const float*)d_in[3];
    const float* w2 = (const float*)d_in[4];
    const float* b2 = (const float*)d_in[5];
    float* out = (float*)d_out;

    // workspace layout (floats)
    float* ws = (float*)d_ws;
    float* attn = ws;                       // B*K*HW = 1,245,184 (reused as rel/attn2)
    float* ocr = attn + (size_t)BB * KK * HWHW;  // 38,912
    float* ocr2 = ocr + (size_t)BB * CC * KK;    // 38,912
    float* w2a = ocr2 + (size_t)BB * CC * KK;    // 12,996
    float* bcon = w2a + (size_t)BB * KK * KK * 9; // 171
    float* wTr = bcon + KK * 9;                   // 87,552

    // zero the ocr accumulator
    hipMemsetAsync(ocr, 0, (size_t)BB * CC * KK * sizeof(float), stream);

    softmax_rows<<<BB * KK, 256, 0, stream>>>(ctx, attn);
    ocr_kernel<<<dim3(CC / 16, BB, NSPLIT), 256, 0, stream>>>(feature, attn, ocr);
    ocr2_kernel<<<dim3(CC, BB), 64, 0, stream>>>(w1, ocr, ocr2);
    wtr_kernel<<<(CC * 171 + 255) / 256, 256, 0, stream>>>(w2, wTr);
    w2a_kernel<<<dim3(KK, 9, BB), 64, 0, stream>>>(w2, ocr2, b1, w2a, bcon);
    rel_kernel<<<dim3(HWHW / 256, BB), 256, 0, stream>>>(feature, ocr, attn);  // rel into attn buf
    softmax_rows<<<BB * KK, 256, 0, stream>>>(attn, attn);                     // attn2 in place
    out_kernel<<<dim3(HH / 2, BB), 256, 0, stream>>>(feature, attn, wTr, w2a, bcon, b2, out);
}

// Round 5
// 551.106 us; speedup vs baseline: 1.8665x; 1.8665x over previous
//
#include <hip/hip_runtime.h>
#include <math.h>

// OCRHead optimized decomposition:
//   attn  = softmax(ctx)                                  [B,K,HW]
//   ocr   = Feature @ attn^T  (per b: [C,HW]x[HW,K])      [B,C,K]
//   ocr2  = W1 @ ocr          (tiny GEMM, replaces 1x1 conv on full map)
//   rel   = ocr^T @ Feature                               [B,K,HW]
//   attn2 = softmax(rel)      (in place)
//   w2a[b]= w2_left . ocr2[b] (19x19x9), bcon = w2_left . b1
//   out   = b2 + masked(bcon) + conv3x3(attn2, w2a) + conv3x3(feature, w2_right)
//
// R3 lesson: pixel-parallelism alone (65536 lanes) = 1 wave/SIMD = latency-bound
// (out_kernel was 670us at 11.9% occupancy, 15.9% VALUBusy). Split the C
// reduction across blocks + fp32 atomics to reach full occupancy.

#define BB 4
#define KK 19
#define CC 512
#define HH 128
#define WW 128
#define HWHW (HH*WW)

// ---------------- softmax over rows of length HW ----------------
__global__ __launch_bounds__(256) void softmax_rows(const float* __restrict__ in,
                                                    float* __restrict__ out) {
    int row = blockIdx.x;
    const float* r = in + (size_t)row * HWHW;
    float* o = out + (size_t)row * HWHW;
    int t = threadIdx.x;
    float v[64];
    float m = -1e30f;
#pragma unroll
    for (int i = 0; i < 64; ++i) { v[i] = r[t + i * 256]; m = fmaxf(m, v[i]); }
    for (int off = 32; off; off >>= 1) m = fmaxf(m, __shfl_xor(m, off));
    __shared__ float sm[4], ss[4];
    int wave = t >> 6;
    if ((t & 63) == 0) sm[wave] = m;
    __syncthreads();
    m = fmaxf(fmaxf(sm[0], sm[1]), fmaxf(sm[2], sm[3]));
    float s = 0.f;
#pragma unroll
    for (int i = 0; i < 64; ++i) { v[i] = __expf(v[i] - m); s += v[i]; }
    for (int off = 32; off; off >>= 1) s += __shfl_xor(s, off);
    if ((t & 63) == 0) ss[wave] = s;
    __syncthreads();
    s = ss[0] + ss[1] + ss[2] + ss[3];
    float inv = 1.f / s;
#pragma unroll
    for (int i = 0; i < 64; ++i) o[t + i * 256] = v[i] * inv;
}

// ---------------- ocr[b,c,k] = sum_n attn[b,k,n]*feature[b,c,n] ----------------
#define NSPLIT 8
__global__ __launch_bounds__(256) void ocr_kernel(const float* __restrict__ feature,
                                                  const float* __restrict__ attn,
                                                  float* __restrict__ ocr) {
    int ctile = blockIdx.x, b = blockIdx.y, ns = blockIdx.z;
    int t = threadIdx.x, wave = t >> 6, lane = t & 63;
    int c0 = ctile * 16 + wave * 4;
    const float* fbase = feature + (size_t)b * CC * HWHW;
    const float* abase = attn + (size_t)b * KK * HWHW;
    float acc[4][KK];
#pragma unroll
    for (int j = 0; j < 4; ++j)
#pragma unroll
        for (int k = 0; k < KK; ++k) acc[j][k] = 0.f;
    int nstart = ns * (HWHW / NSPLIT);
    for (int it = 0; it < (HWHW / NSPLIT) / 64; ++it) {
        int n = nstart + it * 64 + lane;
        float a[KK];
#pragma unroll
        for (int k = 0; k < KK; ++k) a[k] = abase[(size_t)k * HWHW + n];
#pragma unroll
        for (int j = 0; j < 4; ++j) {
            float f = fbase[(size_t)(c0 + j) * HWHW + n];
#pragma unroll
            for (int k = 0; k < KK; ++k) acc[j][k] += f * a[k];
        }
    }
#pragma unroll
    for (int j = 0; j < 4; ++j)
#pragma unroll
        for (int k = 0; k < KK; ++k) {
            float x = acc[j][k];
            for (int off = 32; off; off >>= 1) x += __shfl_xor(x, off);
            if (lane == 0) atomicAdd(&ocr[((size_t)b * CC + (c0 + j)) * KK + k], x);
        }
}

// ---------------- ocr2[b,co,k] = sum_ci w1[co,ci]*ocr[b,ci,k] ----------------
__global__ __launch_bounds__(64) void ocr2_kernel(const float* __restrict__ w1,
                                                  const float* __restrict__ ocr,
                                                  float* __restrict__ ocr2) {
    int co = blockIdx.x, b = blockIdx.y, lane = threadIdx.x;
    float acc[KK];
#pragma unroll
    for (int k = 0; k < KK; ++k) acc[k] = 0.f;
    const float* wrow = w1 + (size_t)co * CC;
    const float* ob = ocr + (size_t)b * CC * KK;
    for (int ci = lane; ci < CC; ci += 64) {
        float w = wrow[ci];
#pragma unroll
        for (int k = 0; k < KK; ++k) acc[k] += w * ob[ci * KK + k];
    }
#pragma unroll
    for (int k = 0; k < KK; ++k) {
        float x = acc[k];
        for (int off = 32; off; off >>= 1) x += __shfl_xor(x, off);
        if (lane == 0) ocr2[((size_t)b * CC + co) * KK + k] = x;
    }
}

// ---------------- transpose right-half conv weights: wTr[c][ko*9+dydx] ----------------
__global__ __launch_bounds__(256) void wtr_kernel(const float* __restrict__ w2,
                                                  float* __restrict__ wTr) {
    int idx = blockIdx.x * 256 + threadIdx.x;
    if (idx >= CC * 171) return;
    int c = idx / 171, j = idx % 171;
    int ko = j / 9, dydx = j % 9;
    wTr[idx] = w2[((size_t)ko * (2 * CC) + CC + c) * 9 + dydx];
}

// ---------------- w2a[b,ko,k,dydx] = sum_c w2[ko,c,dydx]*ocr2[b,c,k]; bcon = w2_left.b1 ----------------
__global__ __launch_bounds__(64) void w2a_kernel(const float* __restrict__ w2,
                                                 const float* __restrict__ ocr2,
                                                 const float* __restrict__ b1,
                                                 float* __restrict__ w2a,
                                                 float* __restrict__ bcon) {
    int ko = blockIdx.x, dydx = blockIdx.y, b = blockIdx.z, lane = threadIdx.x;
    float acc[KK];
#pragma unroll
    for (int k = 0; k < KK; ++k) acc[k] = 0.f;
    float accb = 0.f;
    for (int c = lane; c < CC; c += 64) {
        float wv = w2[((size_t)ko * (2 * CC) + c) * 9 + dydx];
#pragma unroll
        for (int k = 0; k < KK; ++k) acc[k] += wv * ocr2[((size_t)b * CC + c) * KK + k];
        accb += wv * b1[c];
    }
#pragma unroll
    for (int k = 0; k < KK; ++k) {
        float x = acc[k];
        for (int off = 32; off; off >>= 1) x += __shfl_xor(x, off);
        if (lane == 0) w2a[(((size_t)b * KK + ko) * KK + k) * 9 + dydx] = x;
    }
    for (int off = 32; off; off >>= 1) accb += __shfl_xor(accb, off);
    if (lane == 0 && b == 0) bcon[ko * 9 + dydx] = accb;
}

// ---------------- rel[b,k,n] += sum_{ci in chunk} feature[b,ci,n]*ocr[b,ci,k] ----------------
// C split 4-ways across blockIdx.z; fp32 atomics into zeroed rel buffer.
#define NSREL 4
__global__ __launch_bounds__(256) void rel_kernel(const float* __restrict__ feature,
                                                  const float* __restrict__ ocr,
                                                  float* __restrict__ rel) {
    int b = blockIdx.y, ns = blockIdx.z;
    int n = blockIdx.x * 256 + threadIdx.x;
    int cbase = ns * (CC / NSREL);
    const float* fb = feature + ((size_t)b * CC + cbase) * HWHW + n;
    const float* ob = ocr + ((size_t)b * CC + cbase) * KK;  // wave-uniform -> s_load
    float acc[KK];
#pragma unroll
    for (int k = 0; k < KK; ++k) acc[k] = 0.f;
    for (int ci = 0; ci < CC / NSREL; ++ci) {
        float f = fb[(size_t)ci * HWHW];
#pragma unroll
        for (int k = 0; k < KK; ++k) acc[k] += ob[ci * KK + k] * f;
    }
#pragma unroll
    for (int k = 0; k < KK; ++k)
        atomicAdd(&rel[((size_t)b * KK + k) * HWHW + n], acc[k]);
}

// ---------------- final: out += partial conv; C split 8-ways ----------------
// grid (64 ytiles, B, 8 c-chunks), block 256 (2 rows of 128). out pre-zeroed.
#define NSOUT 8
__global__ __launch_bounds__(256) void out_kernel(const float* __restrict__ feature,
                                                  const float* __restrict__ attn2,
                                                  const float* __restrict__ wTr,
                                                  const float* __restrict__ w2a,
                                                  const float* __restrict__ bcon,
                                                  const float* __restrict__ b2,
                                                  float* __restrict__ out) {
    int b = blockIdx.y, ns = blockIdx.z;
    int t = threadIdx.x;
    int y = blockIdx.x * 2 + (t >> 7);
    int x = t & 127;

    float m[9];
    int off[9];
#pragma unroll
    for (int dy = -1; dy <= 1; ++dy)
#pragma unroll
        for (int dx = -1; dx <= 1; ++dx) {
            int i = (dy + 1) * 3 + (dx + 1);
            int yy = y + dy, xx = x + dx;
            bool valid = (yy >= 0 && yy < HH && xx >= 0 && xx < WW);
            m[i] = valid ? 1.f : 0.f;
            int yc = min(max(yy, 0), HH - 1), xc = min(max(xx, 0), WW - 1);
            off[i] = yc * WW + xc;
        }

    float acc[KK];
#pragma unroll
    for (int ko = 0; ko < KK; ++ko) acc[ko] = 0.f;

    if (ns == 0) {
        // bias + zero-pad-mask bias + rank-19 attn2 conv
#pragma unroll
        for (int ko = 0; ko < KK; ++ko) acc[ko] = b2[ko];
#pragma unroll
        for (int i = 0; i < 9; ++i)
#pragma unroll
            for (int ko = 0; ko < KK; ++ko) acc[ko] += m[i] * bcon[ko * 9 + i];
        const float* a2b = attn2 + (size_t)b * KK * HWHW;
        const float* wab = w2a + (size_t)b * KK * KK * 9;
        for (int k = 0; k < KK; ++k) {
            float tap[9];
#pragma unroll
            for (int i = 0; i < 9; ++i) tap[i] = m[i] * a2b[(size_t)k * HWHW + off[i]];
#pragma unroll
            for (int ko = 0; ko < KK; ++ko)
#pragma unroll
                for (int i = 0; i < 9; ++i) acc[ko] += wab[(ko * KK + k) * 9 + i] * tap[i];
        }
    }

    // feature conv part, channels [ns*64, ns*64+64); weights wave-uniform -> scalar path
    int cbase = ns * (CC / NSOUT);
    const float* fb = feature + ((size_t)b * CC + cbase) * HWHW;
    for (int cc = 0; cc < CC / NSOUT; ++cc) {
        float tap[9];
#pragma unroll
        for (int i = 0; i < 9; ++i) tap[i] = m[i] * fb[(size_t)cc * HWHW + off[i]];
        const float* wr = wTr + (cbase + cc) * 171;
#pragma unroll
        for (int j = 0; j < 171; ++j) acc[j / 9] += wr[j] * tap[j % 9];
    }

    size_t obase = ((size_t)b * KK) * HWHW + (size_t)y * WW + x;
#pragma unroll
    for (int ko = 0; ko < KK; ++ko) atomicAdd(&out[obase + (size_t)ko * HWHW], acc[ko]);
}

extern "C" void kernel_launch(void* const* d_in, const int* in_sizes, int n_in,
                              void* d_out, int out_size, void* d_ws, size_t ws_size,
                              hipStream_t stream) {
    const float* ctx = (const float*)d_in[0];
    const float* feature = (const float*)d_in[1];
    const float* w1 = (const float*)d_in[2];
    const float* b1 = (const float*)d_in[3];
    const float* w2 = (const float*)d_in[4];
    const float* b2 = (const float*)d_in[5];
    float* out = (float*)d_out;

    // workspace layout (floats)
    float* ws = (float*)d_ws;
    float* attn = ws;                             // B*K*HW (reused as rel/attn2)
    float* ocr = attn + (size_t)BB * KK * HWHW;   // 38,912
    float* ocr2 = ocr + (size_t)BB * CC * KK;     // 38,912
    float* w2a = ocr2 + (size_t)BB * CC * KK;     // 12,996
    float* bcon = w2a + (size_t)BB * KK * KK * 9; // 171
    float* wTr = bcon + KK * 9;                   // 87,552

    hipMemsetAsync(ocr, 0, (size_t)BB * CC * KK * sizeof(float), stream);
    hipMemsetAsync(out, 0, (size_t)out_size * sizeof(float), stream);

    softmax_rows<<<BB * KK, 256, 0, stream>>>(ctx, attn);
    ocr_kernel<<<dim3(CC / 16, BB, NSPLIT), 256, 0, stream>>>(feature, attn, ocr);
    ocr2_kernel<<<dim3(CC, BB), 64, 0, stream>>>(w1, ocr, ocr2);
    wtr_kernel<<<(CC * 171 + 255) / 256, 256, 0, stream>>>(w2, wTr);
    w2a_kernel<<<dim3(KK, 9, BB), 64, 0, stream>>>(w2, ocr2, b1, w2a, bcon);
    // attn no longer needed -> zero it, accumulate rel there atomically
    hipMemsetAsync(attn, 0, (size_t)BB * KK * HWHW * sizeof(float), stream);
    rel_kernel<<<dim3(HWHW / 256, BB, NSREL), 256, 0, stream>>>(feature, ocr, attn);
    softmax_rows<<<BB * KK, 256, 0, stream>>>(attn, attn);  // attn2 in place
    out_kernel<<<dim3(HH / 2, BB, NSOUT), 256, 0, stream>>>(feature, attn, wTr, w2a, bcon, b2, out);
}